// Round 1
// baseline (448.439 us; speedup 1.0000x reference)
//
#include <hip/hip_runtime.h>
#include <hip/hip_bf16.h>
#include <string.h>

// PerformerAttention: out = (relu(xWq^T+bq) @ [relu(xWk^T+bk)^T @ (xWv^T+bv)]_per-head) Wo^T + bo
// B=4 S=8192 E=768 H=12 Dh=64.  All GEMMs: C[m,n] = sum_k A[m,k]*W[n,k] + b[n]  (x @ W.T)
// Workspace layout (bytes), total ~162 MB:
//   0        : Wq_b  (768*768*2 = 1179648)
//   1179648  : Wk_b
//   2359296  : Wv_b
//   3538944  : Wo_b
//   4718592  : Qb   [32768,768] bf16 relu'd   (50331648)
//   55050240 : Kb   [32768,768] bf16 relu'd   (later reused as QKVb)
//   105381888: Vb   [32768,768] bf16
//   155713536: P    partial KV [48*16][64*64] f32 (12582912)
//   168296448: KV   [48][64*64] f32 (786432)   end = 169082880

#define H_  12
#define DH  64
#define E_  768
#define S_  8192
#define B_  4

typedef unsigned short u16;
typedef __attribute__((ext_vector_type(4))) float f32x4;
typedef __attribute__((ext_vector_type(4))) u16   u16x4;
typedef __attribute__((ext_vector_type(8))) u16   u16x8;
typedef __attribute__((ext_vector_type(8))) short s16x8;

static __device__ __forceinline__ u16 f2bf(float f) {
    __hip_bfloat16 h = __float2bfloat16(f);   // RNE via v_cvt hardware
    u16 r; __builtin_memcpy(&r, &h, 2); return r;
}
static __device__ __forceinline__ float bf2f(u16 u) {
    unsigned int i = ((unsigned int)u) << 16;
    float f; __builtin_memcpy(&f, &i, 4); return f;
}

// ---------------- weight f32 -> bf16 ----------------
__global__ __launch_bounds__(256) void wconv(const float* __restrict__ in,
                                             u16* __restrict__ out, int n) {
    int i = (blockIdx.x * 256 + threadIdx.x) * 4;
    if (i + 3 < n) {
        f32x4 v = *(const f32x4*)&in[i];
        u16x4 o;
        o[0] = f2bf(v[0]); o[1] = f2bf(v[1]); o[2] = f2bf(v[2]); o[3] = f2bf(v[3]);
        *(u16x4*)&out[i] = o;
    }
}

// ---------------- bf16 MFMA GEMM, NT (both operands k-contiguous) ----------------
// BM=BN=128, BK=32, 256 threads = 4 waves (2x2), each wave 64x64 = 4x4 16x16 frags.
template<int A_F32, int RELU, int OUT_F32>
__global__ __launch_bounds__(256) void gemm_bt(const void* __restrict__ Ap,
                                               const u16*  __restrict__ Bw,
                                               const float* __restrict__ bias,
                                               void* __restrict__ Cp, int K) {
    __shared__ u16 As[128 * 32];
    __shared__ u16 Bs[128 * 32];
    const int  t    = threadIdx.x;
    const int  lane = t & 63;
    const int  wave = t >> 6;
    const long m0   = (long)blockIdx.x * 128;
    const long n0   = (long)blockIdx.y * 128;
    const int  wr   = (wave >> 1) * 64;
    const int  wc   = (wave & 1) * 64;
    const int  N    = gridDim.y * 128;

    const float* Af = (const float*)Ap;
    const u16*   Ab = (const u16*)Ap;

    f32x4 acc[4][4] = {};

    for (int k0 = 0; k0 < K; k0 += 32) {
        // ---- stage A tile [128][32] ----
        if (A_F32) {
            #pragma unroll
            for (int i = 0; i < 4; ++i) {
                int idx = i * 256 + t;            // float4 index within tile
                int row = idx >> 3;               // 8 float4 per 32-elem row
                int col = (idx & 7) * 4;
                f32x4 v = *(const f32x4*)&Af[(m0 + row) * K + k0 + col];
                u16x4 o;
                o[0] = f2bf(v[0]); o[1] = f2bf(v[1]); o[2] = f2bf(v[2]); o[3] = f2bf(v[3]);
                *(u16x4*)&As[row * 32 + col] = o;
            }
        } else {
            #pragma unroll
            for (int i = 0; i < 2; ++i) {
                int e   = i * 2048 + t * 8;
                int row = e >> 5;
                int col = e & 31;
                *(u16x8*)&As[e] = *(const u16x8*)&Ab[(m0 + row) * K + k0 + col];
            }
        }
        // ---- stage B tile [128][32] (always bf16 weights) ----
        #pragma unroll
        for (int i = 0; i < 2; ++i) {
            int e   = i * 2048 + t * 8;
            int row = e >> 5;
            int col = e & 31;
            *(u16x8*)&Bs[e] = *(const u16x8*)&Bw[(n0 + row) * K + k0 + col];
        }
        __syncthreads();

        // ---- fragments: A lane m = lane&15, k-group = lane>>4 (8 bf16 = b128) ----
        s16x8 af[4], bfr[4];
        #pragma unroll
        for (int mi = 0; mi < 4; ++mi)
            af[mi] = *(const s16x8*)&As[(wr + mi * 16 + (lane & 15)) * 32 + (lane >> 4) * 8];
        #pragma unroll
        for (int ni = 0; ni < 4; ++ni)
            bfr[ni] = *(const s16x8*)&Bs[(wc + ni * 16 + (lane & 15)) * 32 + (lane >> 4) * 8];
        #pragma unroll
        for (int mi = 0; mi < 4; ++mi)
            #pragma unroll
            for (int ni = 0; ni < 4; ++ni)
                acc[mi][ni] = __builtin_amdgcn_mfma_f32_16x16x32_bf16(af[mi], bfr[ni], acc[mi][ni], 0, 0, 0);
        __syncthreads();
    }

    // ---- epilogue: C/D layout col = lane&15, row = (lane>>4)*4 + r ----
    const int cc = lane & 15;
    const int cr = (lane >> 4) * 4;
    float bv[4];
    #pragma unroll
    for (int ni = 0; ni < 4; ++ni) bv[ni] = bias[n0 + wc + ni * 16 + cc];
    #pragma unroll
    for (int mi = 0; mi < 4; ++mi) {
        #pragma unroll
        for (int r = 0; r < 4; ++r) {
            long gm = m0 + wr + mi * 16 + cr + r;
            #pragma unroll
            for (int ni = 0; ni < 4; ++ni) {
                long gn = n0 + wc + ni * 16 + cc;
                float v = acc[mi][ni][r] + bv[ni];
                if (RELU) v = fmaxf(v, 0.0f);
                if (OUT_F32) ((float*)Cp)[gm * N + gn] = v;
                else         ((u16*)Cp)[gm * N + gn]   = f2bf(v);
            }
        }
    }
}

// ---------------- KV partial: P[bh,chunk][d][e] = sum_{l in chunk} K[l,d]*V[l,e] ----------------
__global__ __launch_bounds__(256) void kv_partial(const u16* __restrict__ Kb,
                                                  const u16* __restrict__ Vb,
                                                  float* __restrict__ P) {
    const int bh = blockIdx.x;        // 0..47
    const int ch = blockIdx.y;        // 0..15 (512 l's each)
    const int b  = bh / H_, h = bh % H_;
    const int t  = threadIdx.x;
    __shared__ float Ksf[16 * 64], Vsf[16 * 64];
    const int d = t & 63, e0 = (t >> 6) * 16;
    f32x4 a4[4] = {};
    const long base = ((long)b * S_) * E_ + h * DH;

    for (int it = 0; it < 32; ++it) {
        int l0 = ch * 512 + it * 16;
        {
            int e = t * 4, row = e >> 6, col = e & 63;
            long g = base + (long)(l0 + row) * E_ + col;
            u16x4 kk = *(const u16x4*)&Kb[g];
            u16x4 vv = *(const u16x4*)&Vb[g];
            f32x4 kf, vf;
            #pragma unroll
            for (int j = 0; j < 4; ++j) { kf[j] = bf2f(kk[j]); vf[j] = bf2f(vv[j]); }
            *(f32x4*)&Ksf[e] = kf;
            *(f32x4*)&Vsf[e] = vf;
        }
        __syncthreads();
        #pragma unroll
        for (int l = 0; l < 16; ++l) {
            float kv = Ksf[l * 64 + d];
            const f32x4* vr = (const f32x4*)&Vsf[l * 64 + e0];
            #pragma unroll
            for (int j = 0; j < 4; ++j) a4[j] += kv * vr[j];
        }
        __syncthreads();
    }
    float* Pp = &P[((long)(bh * 16 + ch)) * 4096 + d * 64 + e0];
    #pragma unroll
    for (int j = 0; j < 4; ++j) *(f32x4*)&Pp[j * 4] = a4[j];
}

__global__ __launch_bounds__(256) void kv_reduce(const float* __restrict__ P,
                                                 float* __restrict__ KV) {
    const int bh = blockIdx.x, t = threadIdx.x;
    #pragma unroll
    for (int k = 0; k < 4; ++k) {
        int i = t * 4 + k * 1024;
        f32x4 s = {};
        for (int c = 0; c < 16; ++c) s += *(const f32x4*)&P[((long)(bh * 16 + c)) * 4096 + i];
        *(f32x4*)&KV[(long)bh * 4096 + i] = s;
    }
}

// ---------------- QKV[b,l,h,e] = sum_d Q[b,l,h,d] * KV[b,h,d,e], out bf16 ----------------
__global__ __launch_bounds__(256) void qkv_contract(const u16* __restrict__ Qb,
                                                    const float* __restrict__ KV,
                                                    u16* __restrict__ Ob) {
    const int ch = blockIdx.x;   // 0..63: 128 rows
    const int h  = blockIdx.y;   // 0..11
    const int b  = blockIdx.z;   // 0..3
    const int t  = threadIdx.x;
    __shared__ float KVs[64 * 64];
    __shared__ u16   Qs[128 * 68];   // pad 64->68: stride 136B, conflict-free scalar reads

    const float* KVg = &KV[(long)(b * H_ + h) * 4096];
    #pragma unroll
    for (int i = 0; i < 4; ++i)
        *(f32x4*)&KVs[(i * 256 + t) * 4] = *(const f32x4*)&KVg[(i * 256 + t) * 4];

    const int  r    = t >> 1, c0 = (t & 1) * 32;
    const long rowg = (long)b * S_ + ch * 128 + r;
    #pragma unroll
    for (int j = 0; j < 8; ++j)
        *(u16x4*)&Qs[r * 68 + c0 + j * 4] = *(const u16x4*)&Qb[rowg * E_ + h * DH + c0 + j * 4];
    __syncthreads();

    f32x4 a4[8] = {};
    for (int d = 0; d < 64; ++d) {
        float q = bf2f(Qs[r * 68 + d]);
        const f32x4* kv = (const f32x4*)&KVs[d * 64 + c0];
        #pragma unroll
        for (int j = 0; j < 8; ++j) a4[j] += q * kv[j];
    }
    u16* Op = &Ob[rowg * E_ + h * DH + c0];
    #pragma unroll
    for (int j = 0; j < 8; ++j) {
        u16x4 o;
        #pragma unroll
        for (int x = 0; x < 4; ++x) o[x] = f2bf(a4[j][x]);
        *(u16x4*)&Op[j * 4] = o;
    }
}

extern "C" void kernel_launch(void* const* d_in, const int* in_sizes, int n_in,
                              void* d_out, int out_size, void* d_ws, size_t ws_size,
                              hipStream_t stream) {
    const float* q  = (const float*)d_in[0];
    const float* k  = (const float*)d_in[1];
    const float* v  = (const float*)d_in[2];
    const float* Wq = (const float*)d_in[3];
    const float* bq = (const float*)d_in[4];
    const float* Wk = (const float*)d_in[5];
    const float* bk = (const float*)d_in[6];
    const float* Wv = (const float*)d_in[7];
    const float* bv = (const float*)d_in[8];
    const float* Wo = (const float*)d_in[9];
    const float* bo = (const float*)d_in[10];
    float* out = (float*)d_out;

    char* ws = (char*)d_ws;
    u16*   Wq_b = (u16*)(ws);
    u16*   Wk_b = (u16*)(ws + 1179648L);
    u16*   Wv_b = (u16*)(ws + 2359296L);
    u16*   Wo_b = (u16*)(ws + 3538944L);
    u16*   Qb   = (u16*)(ws + 4718592L);
    u16*   Kb   = (u16*)(ws + 55050240L);
    u16*   Vb   = (u16*)(ws + 105381888L);
    float* P    = (float*)(ws + 155713536L);
    float* KV   = (float*)(ws + 168296448L);
    u16*   QKVb = Kb;   // Kb dead after kv_partial — reuse

    dim3 blk(256);
    wconv<<<576, blk, 0, stream>>>(Wq, Wq_b, 589824);
    wconv<<<576, blk, 0, stream>>>(Wk, Wk_b, 589824);
    wconv<<<576, blk, 0, stream>>>(Wv, Wv_b, 589824);
    wconv<<<576, blk, 0, stream>>>(Wo, Wo_b, 589824);

    dim3 g1(256, 6);  // M=32768/128, N=768/128
    gemm_bt<1, 1, 0><<<g1, blk, 0, stream>>>(q, Wq_b, bq, Qb, 768);
    gemm_bt<1, 1, 0><<<g1, blk, 0, stream>>>(k, Wk_b, bk, Kb, 768);
    gemm_bt<1, 0, 0><<<g1, blk, 0, stream>>>(v, Wv_b, bv, Vb, 768);

    kv_partial<<<dim3(48, 16), blk, 0, stream>>>(Kb, Vb, P);
    kv_reduce<<<48, blk, 0, stream>>>(P, KV);
    qkv_contract<<<dim3(64, 12, 4), blk, 0, stream>>>(Qb, KV, QKVb);

    gemm_bt<0, 0, 1><<<g1, blk, 0, stream>>>(QKVb, Wo_b, bo, out, 768);
}